// Round 1
// baseline (623.315 us; speedup 1.0000x reference)
//
#include <hip/hip_runtime.h>

typedef unsigned short u16;
typedef unsigned int u32;

#define N_NODES 50000
#define NB      64

// ws regions (u16 element offsets). Total 393216 u16 = 786432 bytes.
#define BG_OFF  0         // g-part B: N=4096 cols (j=u*64+w), K=64
#define BT_OFF  262144    // t-part B: N=1024 cols (j=u*32+w), K=64
#define BH_OFF  327680    // h-part B: N=2048 cols (j=u*64+w), K=32

// LDS strides
#define ASTR   72   // A_S row stride (u16): 144B
#define X0STR  66   // x0G row stride in uint2 units (pad 64->66: quads hit different banks)
#define X1STR  98   // x1G row stride in uint2 units (pad 96->98)

typedef __attribute__((ext_vector_type(8))) short short8;
typedef __attribute__((ext_vector_type(4))) float f32x4;
union U4S8 { uint4 u; short8 s; };

__device__ __forceinline__ u16 f2bf(float f) {   // RNE f32 -> bf16
    u32 u = __float_as_uint(f);
    return (u16)((u + 0x7fffu + ((u >> 16) & 1u)) >> 16);
}
__device__ __forceinline__ f32x4 bf4(uint2 q) {  // 4 packed bf16 -> f32x4
    f32x4 r;
    r[0] = __uint_as_float(q.x << 16);
    r[1] = __uint_as_float(q.x & 0xffff0000u);
    r[2] = __uint_as_float(q.y << 16);
    r[3] = __uint_as_float(q.y & 0xffff0000u);
    return r;
}

// ---------------- pack: output-indexed, coalesced uint4 writes, gather reads ----------------
// B-frag layout (16x16x32): slot-in-ntile = ks*512 + (((v>>3)&3)*16 + (j&15))*8 + (v&7)
// BG/BT: ntile = j>>4 with 64 k's (ks=v>>5); BH: K=32, no ks term.
__global__ __launch_bounds__(256)
void pack_kernel(const float* __restrict__ W1, const float* __restrict__ W2,
                 const float* __restrict__ W3, const float* __restrict__ W4,
                 const float* __restrict__ W5, u16* __restrict__ ws) {
    const float INV_SQRT3 = 0.57735026918962576f;
    int T = blockIdx.x * 256 + threadIdx.x;       // 49152 threads
    int slot0 = T * 8;                             // 8 consecutive slots (jj = v&7 = 0..7)
    float vals[8];
    if (slot0 < BT_OFF) {                          // ---- BG: Ŵ0[v, u, w] ----
        int ntile = slot0 >> 10, rem = slot0 & 1023;
        int ks = rem >> 9, q = (rem & 511) >> 3;
        int vbase = ks * 32 + (q >> 4) * 8;
        int j = ntile * 16 + (q & 15);
        int u = j >> 6, w = j & 63;
        #pragma unroll
        for (int jj = 0; jj < 8; ++jj) {
            int v = vbase + jj;
            if (v == u) vals[jj] = W2[u * 64 + w];
            else {
                int a = min(u, v), b = max(u, v);
                int p = a * (127 - a) / 2 + (b - a - 1);   // triu64 k=1 row-major
                vals[jj] = 0.5f * W1[p * 64 + w];
            }
        }
    } else if (slot0 < BH_OFF) {                   // ---- BT: W3[u, v, w], col j=u*32+w ----
        int s = slot0 - BT_OFF;
        int ntile = s >> 10, rem = s & 1023;
        int ks = rem >> 9, q = (rem & 511) >> 3;
        int vbase = ks * 32 + (q >> 4) * 8;
        int j = ntile * 16 + (q & 15);
        int u = j >> 5, w = j & 31;
        #pragma unroll
        for (int jj = 0; jj < 8; ++jj)
            vals[jj] = W3[(u * 64 + (vbase + jj)) * 32 + w];
    } else {                                       // ---- BH: Ŵ1[v, u, w], K=32 ----
        int s = slot0 - BH_OFF;
        int ntile = s >> 9, q = (s & 511) >> 3;
        int vbase = (q >> 4) * 8;
        int j = ntile * 16 + (q & 15);
        int u = j >> 6, w = j & 63;
        #pragma unroll
        for (int jj = 0; jj < 8; ++jj) {
            int v = vbase + jj;
            if (v == u) vals[jj] = W5[u * 64 + w] * INV_SQRT3;
            else {
                int a = min(u, v), b = max(u, v);
                int p = a * (63 - a) / 2 + (b - a - 1);    // triu32 k=1
                vals[jj] = (0.5f * INV_SQRT3) * W4[p * 64 + w];
            }
        }
    }
    uint4 o;
    o.x = ((u32)f2bf(vals[1]) << 16) | f2bf(vals[0]);
    o.y = ((u32)f2bf(vals[3]) << 16) | f2bf(vals[2]);
    o.z = ((u32)f2bf(vals[5]) << 16) | f2bf(vals[4]);
    o.w = ((u32)f2bf(vals[7]) << 16) | f2bf(vals[6]);
    *(uint4*)(ws + slot0) = o;                     // coalesced 16B store
}

// ---------------- main fused kernel: 16 waves/CU, pair-wise K loops, deep prefetch ----------------
__global__ __launch_bounds__(256, 4)
void node_block_kernel(const float* __restrict__ feats, const float* __restrict__ msgs,
                       const u16* __restrict__ ws, float* __restrict__ out) {
    __shared__ u16 A_S[64 * ASTR];           //  9216 B  bf16 x0 tile (rows n, cols v<64) for MFMA A-frags
    __shared__ u16 x0G[16 * X0STR * 4];      //  8448 B  x0 packed [ngroup][v] uint2 (4 nodes/uint2)
    __shared__ u16 x1G[16 * X1STR * 4];      // 12544 B  x1 packed [ngroup][i*32+u] uint2
    // total 30208 B -> 4 blocks/CU at VGPR<=128 (16 waves/CU)

    const int tid = threadIdx.x;
    const int node0 = blockIdx.x * NB;

    // ---- staging: x = feats + msgs, scattered into LDS forms ----
    for (int k = 0; k < 5; ++k) {
        int chunk = tid + k * 256;
        int idx = chunk * 8;                 // 160 % 8 == 0: never straddles nodes
        int n = (u32)idx / 160u;
        int d = idx - n * 160;
        int g = node0 * 160 + idx;
        float v[8];
        if (g + 8 <= N_NODES * 160) {
            float4 fa0 = *(const float4*)(feats + g);
            float4 fa1 = *(const float4*)(feats + g + 4);
            float4 fb0 = *(const float4*)(msgs + g);
            float4 fb1 = *(const float4*)(msgs + g + 4);
            v[0]=fa0.x+fb0.x; v[1]=fa0.y+fb0.y; v[2]=fa0.z+fb0.z; v[3]=fa0.w+fb0.w;
            v[4]=fa1.x+fb1.x; v[5]=fa1.y+fb1.y; v[6]=fa1.z+fb1.z; v[7]=fa1.w+fb1.w;
        } else {
            #pragma unroll
            for (int j = 0; j < 8; ++j) v[j] = 0.f;
        }
        u16 bv[8];
        #pragma unroll
        for (int j = 0; j < 8; ++j) bv[j] = f2bf(v[j]);
        if (d < 64) {                        // x0 chunk
            uint4 pk;
            pk.x = ((u32)bv[1] << 16) | bv[0];
            pk.y = ((u32)bv[3] << 16) | bv[2];
            pk.z = ((u32)bv[5] << 16) | bv[4];
            pk.w = ((u32)bv[7] << 16) | bv[6];
            *(uint4*)&A_S[n * ASTR + d] = pk;
            int b0 = ((n >> 2) * X0STR + d) * 4 + (n & 3);
            #pragma unroll
            for (int j = 0; j < 8; ++j) x0G[b0 + j * 4] = bv[j];
        } else {                             // x1 chunk
            #pragma unroll
            for (int j = 0; j < 8; ++j) {
                int dd = d + j - 64;
                int u = (u32)dd / 3u, i = dd - u * 3;
                x1G[((n >> 2) * X1STR + i * 32 + u) * 4 + (n & 3)] = bv[j];
            }
        }
    }
    __syncthreads();     // the ONLY barrier

    const int wave = tid >> 6, lane = tid & 63, quad = lane >> 4, l15 = lane & 15;
    const int wq = wave;                 // wave owns out0 cols [wq*16, wq*16+16)
    const f32x4 z4 = {0.f, 0.f, 0.f, 0.f};
    const int ph64 = (blockIdx.x * 10) & 62;   // EVEN per-block phase (pairs need u0 even)
    const int ph32 = ph64 & 30;

    f32x4 o0[4];                         // out0 accumulators (live through S and H only)
    #pragma unroll
    for (int mt = 0; mt < 4; ++mt) o0[mt] = z4;

    // ================ stage S: g = x0 @ Ŵ0 (K=64, N=4096), contract with x0 ================
    {
        short8 aS[4][2];
        #pragma unroll
        for (int mt = 0; mt < 4; ++mt)
            #pragma unroll
            for (int ks = 0; ks < 2; ++ks) {
                U4S8 t; t.u = *(const uint4*)&A_S[(mt * 16 + l15) * ASTR + ks * 32 + quad * 8];
                aS[mt][ks] = t.s;
            }
        const u16* bp = ws + BG_OFF + (u32)wq * 1024 + lane * 8;   // + u*4096 per u
        U4S8 bS[2][2][2];                // [pair-buf][t-in-pair][ks], distance-4 prefetch
        #pragma unroll
        for (int buf = 0; buf < 2; ++buf)
            #pragma unroll
            for (int tp = 0; tp < 2; ++tp) {
                int u = (ph64 + buf * 2 + tp) & 63;
                bS[buf][tp][0].u = *(const uint4*)(bp + u * 4096);
                bS[buf][tp][1].u = *(const uint4*)(bp + u * 4096 + 512);
            }
        #pragma unroll 2
        for (int p = 0; p < 32; ++p) {
            const int c = p & 1;
            const int u0 = (ph64 + 2 * p) & 63;     // even; pair handles u0, u0+1
            uint4 xg[4];                             // one uint4 = xq for BOTH u0 and u0+1
            #pragma unroll
            for (int mt = 0; mt < 4; ++mt)
                xg[mt] = *(const uint4*)&x0G[((mt * 4 + quad) * X0STR + u0) * 4];
            short8 B00 = bS[c][0][0].s, B01 = bS[c][0][1].s;
            short8 B10 = bS[c][1][0].s, B11 = bS[c][1][1].s;
            if (p < 30) {                            // prefetch pair p+2
                int ua = (ph64 + 2 * p + 4) & 63;
                bS[c][0][0].u = *(const uint4*)(bp + ua * 4096);
                bS[c][0][1].u = *(const uint4*)(bp + ua * 4096 + 512);
                bS[c][1][0].u = *(const uint4*)(bp + (ua + 1) * 4096);
                bS[c][1][1].u = *(const uint4*)(bp + (ua + 1) * 4096 + 512);
            }
            f32x4 acc[4];
            #pragma unroll
            for (int mt = 0; mt < 4; ++mt) {
                acc[mt] = __builtin_amdgcn_mfma_f32_16x16x32_bf16(aS[mt][0], B00, z4, 0, 0, 0);
                acc[mt] = __builtin_amdgcn_mfma_f32_16x16x32_bf16(aS[mt][1], B01, acc[mt], 0, 0, 0);
            }
            #pragma unroll
            for (int mt = 0; mt < 4; ++mt) {
                uint2 q; q.x = xg[mt].x; q.y = xg[mt].y;
                o0[mt] += bf4(q) * acc[mt];
            }
            #pragma unroll
            for (int mt = 0; mt < 4; ++mt) {
                acc[mt] = __builtin_amdgcn_mfma_f32_16x16x32_bf16(aS[mt][0], B10, z4, 0, 0, 0);
                acc[mt] = __builtin_amdgcn_mfma_f32_16x16x32_bf16(aS[mt][1], B11, acc[mt], 0, 0, 0);
            }
            #pragma unroll
            for (int mt = 0; mt < 4; ++mt) {
                uint2 q; q.x = xg[mt].z; q.y = xg[mt].w;
                o0[mt] += bf4(q) * acc[mt];
            }
        }
    }

    // ================ stage H: h = x1 @ Ŵ1 (K=32, N=2048), merged i, contract -> out0 ================
    {
        short8 aH[12];                   // built from x1G (A_H eliminated)
        #pragma unroll
        for (int i = 0; i < 3; ++i)
            #pragma unroll
            for (int m = 0; m < 4; ++m) {
                const int n = m * 16 + l15;
                const int base = ((n >> 2) * X1STR + i * 32) * 4 + (n & 3);
                union { short8 s; u16 e[8]; } t;
                #pragma unroll
                for (int j = 0; j < 8; ++j)
                    t.e[j] = x1G[base + (quad * 8 + j) * 4];
                aH[i * 4 + m] = t.s;
            }
        const u16* bp = ws + BH_OFF + (u32)wq * 512 + lane * 8;    // + u*2048 per u
        U4S8 bH[2][2];                   // [pair-buf][t-in-pair]
        #pragma unroll
        for (int buf = 0; buf < 2; ++buf)
            #pragma unroll
            for (int tp = 0; tp < 2; ++tp)
                bH[buf][tp].u = *(const uint4*)(bp + ((ph32 + buf * 2 + tp) & 31) * 2048);
        #pragma unroll 2
        for (int p = 0; p < 16; ++p) {
            const int c = p & 1;
            const int u0 = (ph32 + 2 * p) & 31;
            short8 B0 = bH[c][0].s, B1 = bH[c][1].s;
            if (p < 14) {
                int ua = (ph32 + 2 * p + 4) & 31;
                bH[c][0].u = *(const uint4*)(bp + ua * 2048);
                bH[c][1].u = *(const uint4*)(bp + (ua + 1) * 2048);
            }
            #pragma unroll
            for (int i = 0; i < 3; ++i) {
                uint4 xg[4];
                #pragma unroll
                for (int m = 0; m < 4; ++m)
                    xg[m] = *(const uint4*)&x1G[((m * 4 + quad) * X1STR + i * 32 + u0) * 4];
                f32x4 acc[4];
                #pragma unroll
                for (int m = 0; m < 4; ++m)
                    acc[m] = __builtin_amdgcn_mfma_f32_16x16x32_bf16(aH[i * 4 + m], B0, z4, 0, 0, 0);
                #pragma unroll
                for (int m = 0; m < 4; ++m) {
                    uint2 q; q.x = xg[m].x; q.y = xg[m].y;
                    o0[m] += bf4(q) * acc[m];
                }
                #pragma unroll
                for (int m = 0; m < 4; ++m)
                    acc[m] = __builtin_amdgcn_mfma_f32_16x16x32_bf16(aH[i * 4 + m], B1, z4, 0, 0, 0);
                #pragma unroll
                for (int m = 0; m < 4; ++m) {
                    uint2 q; q.x = xg[m].z; q.y = xg[m].w;
                    o0[m] += bf4(q) * acc[m];
                }
            }
        }
    }

    // ---- out0 epilogue (o0 dies here, before stage T) ----
    {
        const float C0v = 0.019581512f;              // sqrt(1/2608)
        #pragma unroll
        for (int mt = 0; mt < 4; ++mt)
            #pragma unroll
            for (int rr = 0; rr < 4; ++rr) {
                int node = node0 + mt * 16 + quad * 4 + rr;
                if (node < N_NODES)
                    out[node * 160 + wq * 16 + l15] = C0v * o0[mt][rr];
            }
    }

    // ================ stage T: t = x0 @ W3' (K=64, N=1024), contract with x1 -> out1 ================
    {
        const int mh = wave >> 1, wh = wave & 1;     // wave owns rows [mh*32..+32), w-cols [wh*16..+16)
        short8 aT[2][2];
        #pragma unroll
        for (int m = 0; m < 2; ++m)
            #pragma unroll
            for (int ks = 0; ks < 2; ++ks) {
                U4S8 t; t.u = *(const uint4*)&A_S[((mh * 2 + m) * 16 + l15) * ASTR + ks * 32 + quad * 8];
                aT[m][ks] = t.s;
            }
        f32x4 o1[3][2];
        #pragma unroll
        for (int i = 0; i < 3; ++i)
            #pragma unroll
            for (int m = 0; m < 2; ++m) o1[i][m] = z4;

        const u16* bp = ws + BT_OFF + (u32)wh * 1024 + lane * 8;   // + u*2048 per u
        U4S8 bT[2][2][2];                // [pair-buf][t-in-pair][ks]
        #pragma unroll
        for (int buf = 0; buf < 2; ++buf)
            #pragma unroll
            for (int tp = 0; tp < 2; ++tp) {
                int u = (ph32 + buf * 2 + tp) & 31;
                bT[buf][tp][0].u = *(const uint4*)(bp + u * 2048);
                bT[buf][tp][1].u = *(const uint4*)(bp + u * 2048 + 512);
            }
        #pragma unroll 2
        for (int p = 0; p < 16; ++p) {
            const int c = p & 1;
            const int u0 = (ph32 + 2 * p) & 31;
            uint4 xg[3][2];
            #pragma unroll
            for (int i = 0; i < 3; ++i)
                #pragma unroll
                for (int m = 0; m < 2; ++m)
                    xg[i][m] = *(const uint4*)&x1G[(((mh * 2 + m) * 4 + quad) * X1STR + i * 32 + u0) * 4];
            short8 B00 = bT[c][0][0].s, B01 = bT[c][0][1].s;
            short8 B10 = bT[c][1][0].s, B11 = bT[c][1][1].s;
            if (p < 14) {
                int ua = (ph32 + 2 * p + 4) & 31;
                bT[c][0][0].u = *(const uint4*)(bp + ua * 2048);
                bT[c][0][1].u = *(const uint4*)(bp + ua * 2048 + 512);
                bT[c][1][0].u = *(const uint4*)(bp + (ua + 1) * 2048);
                bT[c][1][1].u = *(const uint4*)(bp + (ua + 1) * 2048 + 512);
            }
            f32x4 acc[2];
            #pragma unroll
            for (int m = 0; m < 2; ++m) {
                acc[m] = __builtin_amdgcn_mfma_f32_16x16x32_bf16(aT[m][0], B00, z4, 0, 0, 0);
                acc[m] = __builtin_amdgcn_mfma_f32_16x16x32_bf16(aT[m][1], B01, acc[m], 0, 0, 0);
            }
            #pragma unroll
            for (int i = 0; i < 3; ++i)
                #pragma unroll
                for (int m = 0; m < 2; ++m) {
                    uint2 q; q.x = xg[i][m].x; q.y = xg[i][m].y;
                    o1[i][m] += bf4(q) * acc[m];
                }
            #pragma unroll
            for (int m = 0; m < 2; ++m) {
                acc[m] = __builtin_amdgcn_mfma_f32_16x16x32_bf16(aT[m][0], B10, z4, 0, 0, 0);
                acc[m] = __builtin_amdgcn_mfma_f32_16x16x32_bf16(aT[m][1], B11, acc[m], 0, 0, 0);
            }
            #pragma unroll
            for (int i = 0; i < 3; ++i)
                #pragma unroll
                for (int m = 0; m < 2; ++m) {
                    uint2 q; q.x = xg[i][m].z; q.y = xg[i][m].w;
                    o1[i][m] += bf4(q) * acc[m];
                }
        }
        const float S1 = 0.022097087f;               // C1/sqrt(3) = sqrt(1/2048)
        #pragma unroll
        for (int i = 0; i < 3; ++i)
            #pragma unroll
            for (int m = 0; m < 2; ++m)
                #pragma unroll
                for (int rr = 0; rr < 4; ++rr) {
                    int node = node0 + (mh * 2 + m) * 16 + quad * 4 + rr;
                    if (node < N_NODES)
                        out[node * 160 + 64 + (wh * 16 + l15) * 3 + i] = S1 * o1[i][m][rr];
                }
    }
}

extern "C" void kernel_launch(void* const* d_in, const int* in_sizes, int n_in,
                              void* d_out, int out_size, void* d_ws, size_t ws_size,
                              hipStream_t stream) {
    const float* feats = (const float*)d_in[0];
    const float* msgs  = (const float*)d_in[1];
    const float* W1    = (const float*)d_in[2];
    const float* W2    = (const float*)d_in[3];
    const float* W3    = (const float*)d_in[4];
    const float* W4    = (const float*)d_in[5];
    const float* W5    = (const float*)d_in[6];
    float* out = (float*)d_out;
    u16* ws = (u16*)d_ws;     // needs 786432 B

    hipLaunchKernelGGL(pack_kernel, dim3(192), dim3(256), 0, stream,
                       W1, W2, W3, W4, W5, ws);
    hipLaunchKernelGGL(node_block_kernel, dim3((N_NODES + NB - 1) / NB), dim3(256), 0, stream,
                       feats, msgs, ws, out);
}

// Round 2
// 260.396 us; speedup vs baseline: 2.3937x; 2.3937x over previous
//
#include <hip/hip_runtime.h>

typedef unsigned short u16;
typedef unsigned int u32;

#define N_NODES 50000
#define NB      64

// ws regions (u16 element offsets). Total 393216 u16 = 786432 bytes.
#define BG_OFF  0         // g-part B: N=4096 cols (j=u*64+w), K=64
#define BT_OFF  262144    // t-part B: N=1024 cols (j=u*32+w), K=64
#define BH_OFF  327680    // h-part B: N=2048 cols (j=u*64+w), K=32

// LDS strides
#define ASTR   72   // A_S row stride (u16): 144B
#define XTSTR  68   // x0T/x1T row stride (u16 bf16): 136B

typedef __attribute__((ext_vector_type(8))) short short8;
typedef __attribute__((ext_vector_type(4))) float f32x4;
union U4S8 { uint4 u; short8 s; };

__device__ __forceinline__ u16 f2bf(float f) {   // RNE f32 -> bf16
    u32 u = __float_as_uint(f);
    return (u16)((u + 0x7fffu + ((u >> 16) & 1u)) >> 16);
}
__device__ __forceinline__ f32x4 bf4(uint2 q) {  // 4 packed bf16 -> f32x4
    f32x4 r;
    r[0] = __uint_as_float(q.x << 16);
    r[1] = __uint_as_float(q.x & 0xffff0000u);
    r[2] = __uint_as_float(q.y << 16);
    r[3] = __uint_as_float(q.y & 0xffff0000u);
    return r;
}

// ---------------- pack: output-indexed, coalesced uint4 writes, gather reads ----------------
// B-frag layout (16x16x32): slot-in-ntile = ks*512 + (((v>>3)&3)*16 + (j&15))*8 + (v&7)
// BG/BT: ntile = j>>4 with 64 k's (ks=v>>5); BH: K=32, no ks term.
__global__ __launch_bounds__(256)
void pack_kernel(const float* __restrict__ W1, const float* __restrict__ W2,
                 const float* __restrict__ W3, const float* __restrict__ W4,
                 const float* __restrict__ W5, u16* __restrict__ ws) {
    const float INV_SQRT3 = 0.57735026918962576f;
    int T = blockIdx.x * 256 + threadIdx.x;       // 49152 threads
    int slot0 = T * 8;                             // 8 consecutive slots (jj = v&7 = 0..7)
    float vals[8];
    if (slot0 < BT_OFF) {                          // ---- BG: Ŵ0[v, u, w] ----
        int ntile = slot0 >> 10, rem = slot0 & 1023;
        int ks = rem >> 9, q = (rem & 511) >> 3;
        int vbase = ks * 32 + (q >> 4) * 8;
        int j = ntile * 16 + (q & 15);
        int u = j >> 6, w = j & 63;
        #pragma unroll
        for (int jj = 0; jj < 8; ++jj) {
            int v = vbase + jj;
            if (v == u) vals[jj] = W2[u * 64 + w];
            else {
                int a = min(u, v), b = max(u, v);
                int p = a * (127 - a) / 2 + (b - a - 1);   // triu64 k=1 row-major
                vals[jj] = 0.5f * W1[p * 64 + w];
            }
        }
    } else if (slot0 < BH_OFF) {                   // ---- BT: W3[u, v, w], col j=u*32+w ----
        int s = slot0 - BT_OFF;
        int ntile = s >> 10, rem = s & 1023;
        int ks = rem >> 9, q = (rem & 511) >> 3;
        int vbase = ks * 32 + (q >> 4) * 8;
        int j = ntile * 16 + (q & 15);
        int u = j >> 5, w = j & 31;
        #pragma unroll
        for (int jj = 0; jj < 8; ++jj)
            vals[jj] = W3[(u * 64 + (vbase + jj)) * 32 + w];
    } else {                                       // ---- BH: Ŵ1[v, u, w], K=32 ----
        int s = slot0 - BH_OFF;
        int ntile = s >> 9, q = (s & 511) >> 3;
        int vbase = (q >> 4) * 8;
        int j = ntile * 16 + (q & 15);
        int u = j >> 6, w = j & 63;
        #pragma unroll
        for (int jj = 0; jj < 8; ++jj) {
            int v = vbase + jj;
            if (v == u) vals[jj] = W5[u * 64 + w] * INV_SQRT3;
            else {
                int a = min(u, v), b = max(u, v);
                int p = a * (63 - a) / 2 + (b - a - 1);    // triu32 k=1
                vals[jj] = (0.5f * INV_SQRT3) * W4[p * 64 + w];
            }
        }
    }
    uint4 o;
    o.x = ((u32)f2bf(vals[1]) << 16) | f2bf(vals[0]);
    o.y = ((u32)f2bf(vals[3]) << 16) | f2bf(vals[2]);
    o.z = ((u32)f2bf(vals[5]) << 16) | f2bf(vals[4]);
    o.w = ((u32)f2bf(vals[7]) << 16) | f2bf(vals[6]);
    *(uint4*)(ws + slot0) = o;                     // coalesced 16B store
}

// ---------------- main fused kernel: r0 loop structure, A_H eliminated -> 4 blocks/CU ----------------
__global__ __launch_bounds__(256, 4)
void node_block_kernel(const float* __restrict__ feats, const float* __restrict__ msgs,
                       const u16* __restrict__ ws, float* __restrict__ out) {
    __shared__ u16 A_S[64 * ASTR];       //  9216 B  bf16 x0 tile   (rows n, cols v<64)
    __shared__ u16 x0T[64 * XTSTR];      //  8704 B  bf16 x0^T      ([v][n])
    __shared__ u16 x1T[96 * XTSTR];      // 13056 B  bf16 x1^T      ([u*3+i][n])
    // total 30976 B -> 4 blocks/CU at VGPR<=128 (16 waves/CU)

    const int tid = threadIdx.x;
    const int node0 = blockIdx.x * NB;

    // ---- staging: x = feats + msgs, scattered into LDS forms ----
    for (int k = 0; k < 5; ++k) {
        int chunk = tid + k * 256;
        int idx = chunk * 8;                 // 160 % 8 == 0: never straddles nodes
        int n = (u32)idx / 160u;
        int d = idx - n * 160;
        int g = node0 * 160 + idx;
        float v[8];
        if (g + 8 <= N_NODES * 160) {
            float4 fa0 = *(const float4*)(feats + g);
            float4 fa1 = *(const float4*)(feats + g + 4);
            float4 fb0 = *(const float4*)(msgs + g);
            float4 fb1 = *(const float4*)(msgs + g + 4);
            v[0]=fa0.x+fb0.x; v[1]=fa0.y+fb0.y; v[2]=fa0.z+fb0.z; v[3]=fa0.w+fb0.w;
            v[4]=fa1.x+fb1.x; v[5]=fa1.y+fb1.y; v[6]=fa1.z+fb1.z; v[7]=fa1.w+fb1.w;
        } else {
            #pragma unroll
            for (int j = 0; j < 8; ++j) v[j] = 0.f;
        }
        u16 bv[8];
        #pragma unroll
        for (int j = 0; j < 8; ++j) bv[j] = f2bf(v[j]);
        if (d < 64) {                        // x0 chunk
            uint4 pk;
            pk.x = ((u32)bv[1] << 16) | bv[0];
            pk.y = ((u32)bv[3] << 16) | bv[2];
            pk.z = ((u32)bv[5] << 16) | bv[4];
            pk.w = ((u32)bv[7] << 16) | bv[6];
            *(uint4*)&A_S[n * ASTR + d] = pk;
            #pragma unroll
            for (int j = 0; j < 8; ++j) x0T[(d + j) * XTSTR + n] = bv[j];
        } else {                             // x1 chunk: only x1T now (dd = u*3+i directly)
            #pragma unroll
            for (int j = 0; j < 8; ++j)
                x1T[(d + j - 64) * XTSTR + n] = bv[j];
        }
    }
    __syncthreads();     // the ONLY barrier

    const int wave = tid >> 6, lane = tid & 63, quad = lane >> 4, l15 = lane & 15;
    const int wq = wave;                 // wave owns out0 cols [wq*16, wq*16+16)
    const f32x4 z4 = {0.f, 0.f, 0.f, 0.f};
    const int ph64 = (blockIdx.x * 5) & 63;   // per-block K-loop phase (decorrelate L2 lines)
    const int ph32 = (blockIdx.x * 5) & 31;

    f32x4 o0[4];                         // out0 accumulators (live through S and H only)
    #pragma unroll
    for (int mt = 0; mt < 4; ++mt) o0[mt] = z4;

    // ================ stage S: g = x0 @ Ŵ0 (K=64, N=4096), contract with x0 ================
    {
        short8 aS[4][2];
        #pragma unroll
        for (int mt = 0; mt < 4; ++mt)
            #pragma unroll
            for (int ks = 0; ks < 2; ++ks) {
                U4S8 t; t.u = *(const uint4*)&A_S[(mt * 16 + l15) * ASTR + ks * 32 + quad * 8];
                aS[mt][ks] = t.s;
            }
        const u16* bp = ws + BG_OFF + (u32)wq * 1024 + lane * 8;   // + u*4096 per u
        U4S8 b0[2], b1[2];
        b0[0].u = *(const uint4*)(bp + ph64 * 4096);
        b1[0].u = *(const uint4*)(bp + ph64 * 4096 + 512);
        {
            int p1 = ((ph64 + 1) & 63) * 4096;
            b0[1].u = *(const uint4*)(bp + p1);
            b1[1].u = *(const uint4*)(bp + p1 + 512);
        }
        #pragma unroll 2
        for (int t = 0; t < 64; ++t) {
            const int c = t & 1;
            const int u = (ph64 + t) & 63;
            short8 B0 = b0[c].s, B1 = b1[c].s;
            if (t < 62) {                                         // distance-2 prefetch
                int pp = ((ph64 + t + 2) & 63) * 4096;
                b0[c].u = *(const uint4*)(bp + pp);
                b1[c].u = *(const uint4*)(bp + pp + 512);
            }
            f32x4 acc[4];
            #pragma unroll
            for (int mt = 0; mt < 4; ++mt) acc[mt] = z4;
            #pragma unroll
            for (int mt = 0; mt < 4; ++mt)
                acc[mt] = __builtin_amdgcn_mfma_f32_16x16x32_bf16(aS[mt][0], B0, acc[mt], 0, 0, 0);
            #pragma unroll
            for (int mt = 0; mt < 4; ++mt)
                acc[mt] = __builtin_amdgcn_mfma_f32_16x16x32_bf16(aS[mt][1], B1, acc[mt], 0, 0, 0);
            #pragma unroll
            for (int mt = 0; mt < 4; ++mt) {
                f32x4 xq = bf4(*(const uint2*)&x0T[u * XTSTR + mt * 16 + quad * 4]);
                o0[mt] += xq * acc[mt];
            }
        }
    }

    // ================ stage H: h = x1 @ Ŵ1 (K=32, N=2048), merged i, contract -> out0 ================
    {
        short8 aH[12];                   // built from x1T (A_H eliminated; one-time gather)
        #pragma unroll
        for (int i = 0; i < 3; ++i)
            #pragma unroll
            for (int m = 0; m < 4; ++m) {
                const int n = m * 16 + l15;
                union { short8 s; u16 e[8]; } t;
                #pragma unroll
                for (int j = 0; j < 8; ++j)
                    t.e[j] = x1T[((quad * 8 + j) * 3 + i) * XTSTR + n];
                aH[i * 4 + m] = t.s;
            }
        const u16* bp = ws + BH_OFF + (u32)wq * 512 + lane * 8;    // + u*2048 per u
        U4S8 bb[2];
        bb[0].u = *(const uint4*)(bp + ph32 * 2048);
        bb[1].u = *(const uint4*)(bp + ((ph32 + 1) & 31) * 2048);
        #pragma unroll 2
        for (int t = 0; t < 32; ++t) {
            const int c = t & 1;
            const int u = (ph32 + t) & 31;
            short8 B = bb[c].s;
            if (t < 30) bb[c].u = *(const uint4*)(bp + ((ph32 + t + 2) & 31) * 2048);
            #pragma unroll
            for (int i = 0; i < 3; ++i) {
                f32x4 acc[4];
                #pragma unroll
                for (int m = 0; m < 4; ++m) acc[m] = z4;
                #pragma unroll
                for (int m = 0; m < 4; ++m)
                    acc[m] = __builtin_amdgcn_mfma_f32_16x16x32_bf16(aH[i * 4 + m], B, acc[m], 0, 0, 0);
                #pragma unroll
                for (int m = 0; m < 4; ++m) {
                    f32x4 xq = bf4(*(const uint2*)&x1T[(u * 3 + i) * XTSTR + m * 16 + quad * 4]);
                    o0[m] += xq * acc[m];
                }
            }
        }
    }

    // ---- out0 epilogue (o0 dies here, before stage T) ----
    {
        const float C0v = 0.019581512f;              // sqrt(1/2608)
        #pragma unroll
        for (int mt = 0; mt < 4; ++mt)
            #pragma unroll
            for (int rr = 0; rr < 4; ++rr) {
                int node = node0 + mt * 16 + quad * 4 + rr;
                if (node < N_NODES)
                    out[node * 160 + wq * 16 + l15] = C0v * o0[mt][rr];
            }
    }

    // ================ stage T: t = x0 @ W3' (K=64, N=1024), contract with x1 -> out1 ================
    {
        const int mh = wave >> 1, wh = wave & 1;     // wave owns rows [mh*32..+32), w-cols [wh*16..+16)
        short8 aT[2][2];
        #pragma unroll
        for (int m = 0; m < 2; ++m)
            #pragma unroll
            for (int ks = 0; ks < 2; ++ks) {
                U4S8 t; t.u = *(const uint4*)&A_S[((mh * 2 + m) * 16 + l15) * ASTR + ks * 32 + quad * 8];
                aT[m][ks] = t.s;
            }
        f32x4 o1[3][2];
        #pragma unroll
        for (int i = 0; i < 3; ++i)
            #pragma unroll
            for (int m = 0; m < 2; ++m) o1[i][m] = z4;

        const u16* bp = ws + BT_OFF + (u32)wh * 1024 + lane * 8;   // + u*2048 per u
        U4S8 b0[2], b1[2];
        b0[0].u = *(const uint4*)(bp + ph32 * 2048);
        b1[0].u = *(const uint4*)(bp + ph32 * 2048 + 512);
        {
            int p1 = ((ph32 + 1) & 31) * 2048;
            b0[1].u = *(const uint4*)(bp + p1);
            b1[1].u = *(const uint4*)(bp + p1 + 512);
        }
        #pragma unroll 2
        for (int t = 0; t < 32; ++t) {
            const int c = t & 1;
            const int u = (ph32 + t) & 31;
            short8 B0 = b0[c].s, B1 = b1[c].s;
            if (t < 30) {                                          // distance-2 prefetch
                int pp = ((ph32 + t + 2) & 31) * 2048;
                b0[c].u = *(const uint4*)(bp + pp);
                b1[c].u = *(const uint4*)(bp + pp + 512);
            }
            f32x4 acc[2];
            #pragma unroll
            for (int m = 0; m < 2; ++m) acc[m] = z4;
            #pragma unroll
            for (int m = 0; m < 2; ++m)
                acc[m] = __builtin_amdgcn_mfma_f32_16x16x32_bf16(aT[m][0], B0, acc[m], 0, 0, 0);
            #pragma unroll
            for (int m = 0; m < 2; ++m)
                acc[m] = __builtin_amdgcn_mfma_f32_16x16x32_bf16(aT[m][1], B1, acc[m], 0, 0, 0);
            #pragma unroll
            for (int i = 0; i < 3; ++i)
                #pragma unroll
                for (int m = 0; m < 2; ++m) {
                    f32x4 xq = bf4(*(const uint2*)&x1T[(u * 3 + i) * XTSTR + (mh * 2 + m) * 16 + quad * 4]);
                    o1[i][m] += xq * acc[m];
                }
        }
        const float S1 = 0.022097087f;               // C1/sqrt(3) = sqrt(1/2048)
        #pragma unroll
        for (int i = 0; i < 3; ++i)
            #pragma unroll
            for (int m = 0; m < 2; ++m)
                #pragma unroll
                for (int rr = 0; rr < 4; ++rr) {
                    int node = node0 + (mh * 2 + m) * 16 + quad * 4 + rr;
                    if (node < N_NODES)
                        out[node * 160 + 64 + (wh * 16 + l15) * 3 + i] = S1 * o1[i][m][rr];
                }
    }
}

extern "C" void kernel_launch(void* const* d_in, const int* in_sizes, int n_in,
                              void* d_out, int out_size, void* d_ws, size_t ws_size,
                              hipStream_t stream) {
    const float* feats = (const float*)d_in[0];
    const float* msgs  = (const float*)d_in[1];
    const float* W1    = (const float*)d_in[2];
    const float* W2    = (const float*)d_in[3];
    const float* W3    = (const float*)d_in[4];
    const float* W4    = (const float*)d_in[5];
    const float* W5    = (const float*)d_in[6];
    float* out = (float*)d_out;
    u16* ws = (u16*)d_ws;     // needs 786432 B

    hipLaunchKernelGGL(pack_kernel, dim3(192), dim3(256), 0, stream,
                       W1, W2, W3, W4, W5, ws);
    hipLaunchKernelGGL(node_block_kernel, dim3((N_NODES + NB - 1) / NB), dim3(256), 0, stream,
                       feats, msgs, ws, out);
}

// Round 3
// 194.583 us; speedup vs baseline: 3.2033x; 1.3382x over previous
//
#include <hip/hip_runtime.h>

typedef unsigned short u16;
typedef unsigned int u32;

#define N_NODES 50000
#define NB      64

// ws regions (u16 element offsets). Total 393216 u16 = 786432 bytes.
#define BG_OFF  0         // g-part B: N=4096 cols (j=u*64+w), K=64
#define BT_OFF  262144    // t-part B: N=1024 cols (j=u*32+w), K=64
#define BH_OFF  327680    // h-part B: N=2048 cols (j=u*64+w), K=32

// LDS strides
#define ASTR   72   // A_S row stride (u16): 144B
#define XTSTR  68   // x0T/x1T row stride (u16 bf16): 136B

typedef __attribute__((ext_vector_type(8))) short short8;
typedef __attribute__((ext_vector_type(4))) float f32x4;
union U4S8 { uint4 u; short8 s; };

__device__ __forceinline__ u16 f2bf(float f) {   // RNE f32 -> bf16
    u32 u = __float_as_uint(f);
    return (u16)((u + 0x7fffu + ((u >> 16) & 1u)) >> 16);
}
__device__ __forceinline__ f32x4 bf4(uint2 q) {  // 4 packed bf16 -> f32x4
    f32x4 r;
    r[0] = __uint_as_float(q.x << 16);
    r[1] = __uint_as_float(q.x & 0xffff0000u);
    r[2] = __uint_as_float(q.y << 16);
    r[3] = __uint_as_float(q.y & 0xffff0000u);
    return r;
}

// ---------------- pack: output-indexed, coalesced uint4 writes, gather reads ----------------
// B-frag layout (16x16x32): slot-in-ntile = ks*512 + (((v>>3)&3)*16 + (j&15))*8 + (v&7)
// BG/BT: ntile = j>>4 with 64 k's (ks=v>>5); BH: K=32, no ks term.
__global__ __launch_bounds__(256)
void pack_kernel(const float* __restrict__ W1, const float* __restrict__ W2,
                 const float* __restrict__ W3, const float* __restrict__ W4,
                 const float* __restrict__ W5, u16* __restrict__ ws) {
    const float INV_SQRT3 = 0.57735026918962576f;
    int T = blockIdx.x * 256 + threadIdx.x;       // 49152 threads
    int slot0 = T * 8;                             // 8 consecutive slots (jj = v&7 = 0..7)
    float vals[8];
    if (slot0 < BT_OFF) {                          // ---- BG: Ŵ0[v, u, w] ----
        int ntile = slot0 >> 10, rem = slot0 & 1023;
        int ks = rem >> 9, q = (rem & 511) >> 3;
        int vbase = ks * 32 + (q >> 4) * 8;
        int j = ntile * 16 + (q & 15);
        int u = j >> 6, w = j & 63;
        #pragma unroll
        for (int jj = 0; jj < 8; ++jj) {
            int v = vbase + jj;
            if (v == u) vals[jj] = W2[u * 64 + w];
            else {
                int a = min(u, v), b = max(u, v);
                int p = a * (127 - a) / 2 + (b - a - 1);   // triu64 k=1 row-major
                vals[jj] = 0.5f * W1[p * 64 + w];
            }
        }
    } else if (slot0 < BH_OFF) {                   // ---- BT: W3[u, v, w], col j=u*32+w ----
        int s = slot0 - BT_OFF;
        int ntile = s >> 10, rem = s & 1023;
        int ks = rem >> 9, q = (rem & 511) >> 3;
        int vbase = ks * 32 + (q >> 4) * 8;
        int j = ntile * 16 + (q & 15);
        int u = j >> 5, w = j & 31;
        #pragma unroll
        for (int jj = 0; jj < 8; ++jj)
            vals[jj] = W3[(u * 64 + (vbase + jj)) * 32 + w];
    } else {                                       // ---- BH: Ŵ1[v, u, w], K=32 ----
        int s = slot0 - BH_OFF;
        int ntile = s >> 9, q = (s & 511) >> 3;
        int vbase = (q >> 4) * 8;
        int j = ntile * 16 + (q & 15);
        int u = j >> 6, w = j & 63;
        #pragma unroll
        for (int jj = 0; jj < 8; ++jj) {
            int v = vbase + jj;
            if (v == u) vals[jj] = W5[u * 64 + w] * INV_SQRT3;
            else {
                int a = min(u, v), b = max(u, v);
                int p = a * (63 - a) / 2 + (b - a - 1);    // triu32 k=1
                vals[jj] = (0.5f * INV_SQRT3) * W4[p * 64 + w];
            }
        }
    }
    uint4 o;
    o.x = ((u32)f2bf(vals[1]) << 16) | f2bf(vals[0]);
    o.y = ((u32)f2bf(vals[3]) << 16) | f2bf(vals[2]);
    o.z = ((u32)f2bf(vals[5]) << 16) | f2bf(vals[4]);
    o.w = ((u32)f2bf(vals[7]) << 16) | f2bf(vals[6]);
    *(uint4*)(ws + slot0) = o;                     // coalesced 16B store
}

// ---------------- main fused kernel: r0 loop structure, A_H eliminated, (256,3) = no spill ----------------
// VGPR target ~80 (r0-proven). At 80 VGPR the HW occupancy step gives 4 waves/SIMD ->
// 4 blocks/CU; LDS 30976B allows 5. So 4 blocks/CU WITHOUT forcing the allocator to 64.
__global__ __launch_bounds__(256, 3)
void node_block_kernel(const float* __restrict__ feats, const float* __restrict__ msgs,
                       const u16* __restrict__ ws, float* __restrict__ out) {
    __shared__ u16 A_S[64 * ASTR];       //  9216 B  bf16 x0 tile   (rows n, cols v<64)
    __shared__ u16 x0T[64 * XTSTR];      //  8704 B  bf16 x0^T      ([v][n])
    __shared__ u16 x1T[96 * XTSTR];      // 13056 B  bf16 x1^T      ([u*3+i][n])
    // total 30976 B

    const int tid = threadIdx.x;
    const int node0 = blockIdx.x * NB;

    // ---- staging: x = feats + msgs, scattered into LDS forms ----
    for (int k = 0; k < 5; ++k) {
        int chunk = tid + k * 256;
        int idx = chunk * 8;                 // 160 % 8 == 0: never straddles nodes
        int n = (u32)idx / 160u;
        int d = idx - n * 160;
        int g = node0 * 160 + idx;
        float v[8];
        if (g + 8 <= N_NODES * 160) {
            float4 fa0 = *(const float4*)(feats + g);
            float4 fa1 = *(const float4*)(feats + g + 4);
            float4 fb0 = *(const float4*)(msgs + g);
            float4 fb1 = *(const float4*)(msgs + g + 4);
            v[0]=fa0.x+fb0.x; v[1]=fa0.y+fb0.y; v[2]=fa0.z+fb0.z; v[3]=fa0.w+fb0.w;
            v[4]=fa1.x+fb1.x; v[5]=fa1.y+fb1.y; v[6]=fa1.z+fb1.z; v[7]=fa1.w+fb1.w;
        } else {
            #pragma unroll
            for (int j = 0; j < 8; ++j) v[j] = 0.f;
        }
        u16 bv[8];
        #pragma unroll
        for (int j = 0; j < 8; ++j) bv[j] = f2bf(v[j]);
        if (d < 64) {                        // x0 chunk
            uint4 pk;
            pk.x = ((u32)bv[1] << 16) | bv[0];
            pk.y = ((u32)bv[3] << 16) | bv[2];
            pk.z = ((u32)bv[5] << 16) | bv[4];
            pk.w = ((u32)bv[7] << 16) | bv[6];
            *(uint4*)&A_S[n * ASTR + d] = pk;
            #pragma unroll
            for (int j = 0; j < 8; ++j) x0T[(d + j) * XTSTR + n] = bv[j];
        } else {                             // x1 chunk: only x1T now (dd = u*3+i directly)
            #pragma unroll
            for (int j = 0; j < 8; ++j)
                x1T[(d + j - 64) * XTSTR + n] = bv[j];
        }
    }
    __syncthreads();     // the ONLY barrier

    const int wave = tid >> 6, lane = tid & 63, quad = lane >> 4, l15 = lane & 15;
    const int wq = wave;                 // wave owns out0 cols [wq*16, wq*16+16)
    const f32x4 z4 = {0.f, 0.f, 0.f, 0.f};
    const int ph64 = (blockIdx.x * 5) & 63;   // per-block K-loop phase (decorrelate L2 lines)
    const int ph32 = (blockIdx.x * 5) & 31;

    f32x4 o0[4];                         // out0 accumulators (live through S and H only)
    #pragma unroll
    for (int mt = 0; mt < 4; ++mt) o0[mt] = z4;

    // ================ stage S: g = x0 @ Ŵ0 (K=64, N=4096), contract with x0 ================
    {
        short8 aS[4][2];
        #pragma unroll
        for (int mt = 0; mt < 4; ++mt)
            #pragma unroll
            for (int ks = 0; ks < 2; ++ks) {
                U4S8 t; t.u = *(const uint4*)&A_S[(mt * 16 + l15) * ASTR + ks * 32 + quad * 8];
                aS[mt][ks] = t.s;
            }
        const u16* bp = ws + BG_OFF + (u32)wq * 1024 + lane * 8;   // + u*4096 per u
        U4S8 b0[2], b1[2];
        b0[0].u = *(const uint4*)(bp + ph64 * 4096);
        b1[0].u = *(const uint4*)(bp + ph64 * 4096 + 512);
        {
            int p1 = ((ph64 + 1) & 63) * 4096;
            b0[1].u = *(const uint4*)(bp + p1);
            b1[1].u = *(const uint4*)(bp + p1 + 512);
        }
        #pragma unroll 2
        for (int t = 0; t < 64; ++t) {
            const int c = t & 1;
            const int u = (ph64 + t) & 63;
            short8 B0 = b0[c].s, B1 = b1[c].s;
            if (t < 62) {                                         // distance-2 prefetch
                int pp = ((ph64 + t + 2) & 63) * 4096;
                b0[c].u = *(const uint4*)(bp + pp);
                b1[c].u = *(const uint4*)(bp + pp + 512);
            }
            f32x4 acc[4];
            #pragma unroll
            for (int mt = 0; mt < 4; ++mt) acc[mt] = z4;
            #pragma unroll
            for (int mt = 0; mt < 4; ++mt)
                acc[mt] = __builtin_amdgcn_mfma_f32_16x16x32_bf16(aS[mt][0], B0, acc[mt], 0, 0, 0);
            #pragma unroll
            for (int mt = 0; mt < 4; ++mt)
                acc[mt] = __builtin_amdgcn_mfma_f32_16x16x32_bf16(aS[mt][1], B1, acc[mt], 0, 0, 0);
            #pragma unroll
            for (int mt = 0; mt < 4; ++mt) {
                f32x4 xq = bf4(*(const uint2*)&x0T[u * XTSTR + mt * 16 + quad * 4]);
                o0[mt] += xq * acc[mt];
            }
        }
    }

    // ================ stage H: h = x1 @ Ŵ1 (K=32, N=2048), merged i, contract -> out0 ================
    {
        short8 aH[12];                   // built from x1T (A_H eliminated; one-time gather)
        #pragma unroll
        for (int i = 0; i < 3; ++i)
            #pragma unroll
            for (int m = 0; m < 4; ++m) {
                const int n = m * 16 + l15;
                union { short8 s; u16 e[8]; } t;
                #pragma unroll
                for (int j = 0; j < 8; ++j)
                    t.e[j] = x1T[((quad * 8 + j) * 3 + i) * XTSTR + n];
                aH[i * 4 + m] = t.s;
            }
        const u16* bp = ws + BH_OFF + (u32)wq * 512 + lane * 8;    // + u*2048 per u
        U4S8 bb[2];
        bb[0].u = *(const uint4*)(bp + ph32 * 2048);
        bb[1].u = *(const uint4*)(bp + ((ph32 + 1) & 31) * 2048);
        #pragma unroll 2
        for (int t = 0; t < 32; ++t) {
            const int c = t & 1;
            const int u = (ph32 + t) & 31;
            short8 B = bb[c].s;
            if (t < 30) bb[c].u = *(const uint4*)(bp + ((ph32 + t + 2) & 31) * 2048);
            #pragma unroll
            for (int i = 0; i < 3; ++i) {
                f32x4 acc[4];
                #pragma unroll
                for (int m = 0; m < 4; ++m) acc[m] = z4;
                #pragma unroll
                for (int m = 0; m < 4; ++m)
                    acc[m] = __builtin_amdgcn_mfma_f32_16x16x32_bf16(aH[i * 4 + m], B, acc[m], 0, 0, 0);
                #pragma unroll
                for (int m = 0; m < 4; ++m) {
                    f32x4 xq = bf4(*(const uint2*)&x1T[(u * 3 + i) * XTSTR + m * 16 + quad * 4]);
                    o0[m] += xq * acc[m];
                }
            }
        }
    }

    // ---- out0 epilogue (o0 dies here, before stage T) ----
    {
        const float C0v = 0.019581512f;              // sqrt(1/2608)
        #pragma unroll
        for (int mt = 0; mt < 4; ++mt)
            #pragma unroll
            for (int rr = 0; rr < 4; ++rr) {
                int node = node0 + mt * 16 + quad * 4 + rr;
                if (node < N_NODES)
                    out[node * 160 + wq * 16 + l15] = C0v * o0[mt][rr];
            }
    }

    // ================ stage T: t = x0 @ W3' (K=64, N=1024), contract with x1 -> out1 ================
    {
        const int mh = wave >> 1, wh = wave & 1;     // wave owns rows [mh*32..+32), w-cols [wh*16..+16)
        short8 aT[2][2];
        #pragma unroll
        for (int m = 0; m < 2; ++m)
            #pragma unroll
            for (int ks = 0; ks < 2; ++ks) {
                U4S8 t; t.u = *(const uint4*)&A_S[((mh * 2 + m) * 16 + l15) * ASTR + ks * 32 + quad * 8];
                aT[m][ks] = t.s;
            }
        f32x4 o1[3][2];
        #pragma unroll
        for (int i = 0; i < 3; ++i)
            #pragma unroll
            for (int m = 0; m < 2; ++m) o1[i][m] = z4;

        const u16* bp = ws + BT_OFF + (u32)wh * 1024 + lane * 8;   // + u*2048 per u
        U4S8 b0[2], b1[2];
        b0[0].u = *(const uint4*)(bp + ph32 * 2048);
        b1[0].u = *(const uint4*)(bp + ph32 * 2048 + 512);
        {
            int p1 = ((ph32 + 1) & 31) * 2048;
            b0[1].u = *(const uint4*)(bp + p1);
            b1[1].u = *(const uint4*)(bp + p1 + 512);
        }
        #pragma unroll 2
        for (int t = 0; t < 32; ++t) {
            const int c = t & 1;
            const int u = (ph32 + t) & 31;
            short8 B0 = b0[c].s, B1 = b1[c].s;
            if (t < 30) {                                          // distance-2 prefetch
                int pp = ((ph32 + t + 2) & 31) * 2048;
                b0[c].u = *(const uint4*)(bp + pp);
                b1[c].u = *(const uint4*)(bp + pp + 512);
            }
            f32x4 acc[2];
            #pragma unroll
            for (int m = 0; m < 2; ++m) acc[m] = z4;
            #pragma unroll
            for (int m = 0; m < 2; ++m)
                acc[m] = __builtin_amdgcn_mfma_f32_16x16x32_bf16(aT[m][0], B0, acc[m], 0, 0, 0);
            #pragma unroll
            for (int m = 0; m < 2; ++m)
                acc[m] = __builtin_amdgcn_mfma_f32_16x16x32_bf16(aT[m][1], B1, acc[m], 0, 0, 0);
            #pragma unroll
            for (int i = 0; i < 3; ++i)
                #pragma unroll
                for (int m = 0; m < 2; ++m) {
                    f32x4 xq = bf4(*(const uint2*)&x1T[(u * 3 + i) * XTSTR + (mh * 2 + m) * 16 + quad * 4]);
                    o1[i][m] += xq * acc[m];
                }
        }
        const float S1 = 0.022097087f;               // C1/sqrt(3) = sqrt(1/2048)
        #pragma unroll
        for (int i = 0; i < 3; ++i)
            #pragma unroll
            for (int m = 0; m < 2; ++m)
                #pragma unroll
                for (int rr = 0; rr < 4; ++rr) {
                    int node = node0 + (mh * 2 + m) * 16 + quad * 4 + rr;
                    if (node < N_NODES)
                        out[node * 160 + 64 + (wh * 16 + l15) * 3 + i] = S1 * o1[i][m][rr];
                }
    }
}

extern "C" void kernel_launch(void* const* d_in, const int* in_sizes, int n_in,
                              void* d_out, int out_size, void* d_ws, size_t ws_size,
                              hipStream_t stream) {
    const float* feats = (const float*)d_in[0];
    const float* msgs  = (const float*)d_in[1];
    const float* W1    = (const float*)d_in[2];
    const float* W2    = (const float*)d_in[3];
    const float* W3    = (const float*)d_in[4];
    const float* W4    = (const float*)d_in[5];
    const float* W5    = (const float*)d_in[6];
    float* out = (float*)d_out;
    u16* ws = (u16*)d_ws;     // needs 786432 B

    hipLaunchKernelGGL(pack_kernel, dim3(192), dim3(256), 0, stream,
                       W1, W2, W3, W4, W5, ws);
    hipLaunchKernelGGL(node_block_kernel, dim3((N_NODES + NB - 1) / NB), dim3(256), 0, stream,
                       feats, msgs, ws, out);
}

// Round 5
// 185.963 us; speedup vs baseline: 3.3518x; 1.0463x over previous
//
#include <hip/hip_runtime.h>

typedef unsigned short u16;
typedef unsigned int u32;

#define N_NODES 50000
#define NB      64

// ws regions (u16 element offsets). Total 393216 u16 = 786432 bytes.
#define BG_OFF  0         // g-part B: N=4096 cols (j=u*64+w), K=64
#define BT_OFF  262144    // t-part B: N=1024 cols (j=u*32+w), K=64
#define BH_OFF  327680    // h-part B: N=2048 cols (j=u*64+w), K=32

// LDS strides
#define ASTR   72   // A_S row stride (u16): 144B
#define XTSTR  68   // x0T/x1T row stride (u16 bf16): 136B

typedef __attribute__((ext_vector_type(8))) short short8;
typedef __attribute__((ext_vector_type(4))) float f32x4;
union U4S8 { uint4 u; short8 s; };

__device__ __forceinline__ u16 f2bf(float f) {   // RNE f32 -> bf16
    u32 u = __float_as_uint(f);
    return (u16)((u + 0x7fffu + ((u >> 16) & 1u)) >> 16);
}
__device__ __forceinline__ f32x4 bf4(uint2 q) {  // 4 packed bf16 -> f32x4
    f32x4 r;
    r[0] = __uint_as_float(q.x << 16);
    r[1] = __uint_as_float(q.x & 0xffff0000u);
    r[2] = __uint_as_float(q.y << 16);
    r[3] = __uint_as_float(q.y & 0xffff0000u);
    return r;
}

// ---------------- pack: output-indexed, coalesced uint4 writes, gather reads ----------------
// B-frag layout (16x16x32): slot-in-ntile = ks*512 + (((v>>3)&3)*16 + (j&15))*8 + (v&7)
// BG/BT: ntile = j>>4 with 64 k's (ks=v>>5); BH: K=32, no ks term.
__global__ __launch_bounds__(256)
void pack_kernel(const float* __restrict__ W1, const float* __restrict__ W2,
                 const float* __restrict__ W3, const float* __restrict__ W4,
                 const float* __restrict__ W5, u16* __restrict__ ws) {
    const float INV_SQRT3 = 0.57735026918962576f;
    int T = blockIdx.x * 256 + threadIdx.x;       // 49152 threads
    int slot0 = T * 8;                             // 8 consecutive slots (jj = v&7 = 0..7)
    float vals[8];
    if (slot0 < BT_OFF) {                          // ---- BG: Ŵ0[v, u, w] ----
        int ntile = slot0 >> 10, rem = slot0 & 1023;
        int ks = rem >> 9, q = (rem & 511) >> 3;
        int vbase = ks * 32 + (q >> 4) * 8;
        int j = ntile * 16 + (q & 15);
        int u = j >> 6, w = j & 63;
        #pragma unroll
        for (int jj = 0; jj < 8; ++jj) {
            int v = vbase + jj;
            if (v == u) vals[jj] = W2[u * 64 + w];
            else {
                int a = min(u, v), b = max(u, v);
                int p = a * (127 - a) / 2 + (b - a - 1);   // triu64 k=1 row-major
                vals[jj] = 0.5f * W1[p * 64 + w];
            }
        }
    } else if (slot0 < BH_OFF) {                   // ---- BT: W3[u, v, w], col j=u*32+w ----
        int s = slot0 - BT_OFF;
        int ntile = s >> 10, rem = s & 1023;
        int ks = rem >> 9, q = (rem & 511) >> 3;
        int vbase = ks * 32 + (q >> 4) * 8;
        int j = ntile * 16 + (q & 15);
        int u = j >> 5, w = j & 31;
        #pragma unroll
        for (int jj = 0; jj < 8; ++jj)
            vals[jj] = W3[(u * 64 + (vbase + jj)) * 32 + w];
    } else {                                       // ---- BH: Ŵ1[v, u, w], K=32 ----
        int s = slot0 - BH_OFF;
        int ntile = s >> 9, q = (s & 511) >> 3;
        int vbase = (q >> 4) * 8;
        int j = ntile * 16 + (q & 15);
        int u = j >> 6, w = j & 63;
        #pragma unroll
        for (int jj = 0; jj < 8; ++jj) {
            int v = vbase + jj;
            if (v == u) vals[jj] = W5[u * 64 + w] * INV_SQRT3;
            else {
                int a = min(u, v), b = max(u, v);
                int p = a * (63 - a) / 2 + (b - a - 1);    // triu32 k=1
                vals[jj] = (0.5f * INV_SQRT3) * W4[p * 64 + w];
            }
        }
    }
    uint4 o;
    o.x = ((u32)f2bf(vals[1]) << 16) | f2bf(vals[0]);
    o.y = ((u32)f2bf(vals[3]) << 16) | f2bf(vals[2]);
    o.z = ((u32)f2bf(vals[5]) << 16) | f2bf(vals[4]);
    o.w = ((u32)f2bf(vals[7]) << 16) | f2bf(vals[6]);
    *(uint4*)(ws + slot0) = o;                     // coalesced 16B store
}

// ---------------- main fused kernel: unconditional ring prefetch (precise vmcnt) ----------------
__global__ __launch_bounds__(256, 3)
void node_block_kernel(const float* __restrict__ feats, const float* __restrict__ msgs,
                       const u16* __restrict__ ws, float* __restrict__ out) {
    __shared__ u16 A_S[64 * ASTR];       //  9216 B  bf16 x0 tile   (rows n, cols v<64)
    __shared__ u16 x0T[64 * XTSTR];      //  8704 B  bf16 x0^T      ([v][n])
    __shared__ u16 x1T[96 * XTSTR];      // 13056 B  bf16 x1^T      ([u*3+i][n])
    // total 30976 B

    const int tid = threadIdx.x;
    const int node0 = blockIdx.x * NB;

    // ---- staging: x = feats + msgs, scattered into LDS forms ----
    for (int k = 0; k < 5; ++k) {
        int chunk = tid + k * 256;
        int idx = chunk * 8;                 // 160 % 8 == 0: never straddles nodes
        int n = (u32)idx / 160u;
        int d = idx - n * 160;
        int g = node0 * 160 + idx;
        float v[8];
        if (g + 8 <= N_NODES * 160) {
            float4 fa0 = *(const float4*)(feats + g);
            float4 fa1 = *(const float4*)(feats + g + 4);
            float4 fb0 = *(const float4*)(msgs + g);
            float4 fb1 = *(const float4*)(msgs + g + 4);
            v[0]=fa0.x+fb0.x; v[1]=fa0.y+fb0.y; v[2]=fa0.z+fb0.z; v[3]=fa0.w+fb0.w;
            v[4]=fa1.x+fb1.x; v[5]=fa1.y+fb1.y; v[6]=fa1.z+fb1.z; v[7]=fa1.w+fb1.w;
        } else {
            #pragma unroll
            for (int j = 0; j < 8; ++j) v[j] = 0.f;
        }
        u16 bv[8];
        #pragma unroll
        for (int j = 0; j < 8; ++j) bv[j] = f2bf(v[j]);
        if (d < 64) {                        // x0 chunk
            uint4 pk;
            pk.x = ((u32)bv[1] << 16) | bv[0];
            pk.y = ((u32)bv[3] << 16) | bv[2];
            pk.z = ((u32)bv[5] << 16) | bv[4];
            pk.w = ((u32)bv[7] << 16) | bv[6];
            *(uint4*)&A_S[n * ASTR + d] = pk;
            #pragma unroll
            for (int j = 0; j < 8; ++j) x0T[(d + j) * XTSTR + n] = bv[j];
        } else {                             // x1 chunk: only x1T now (dd = u*3+i directly)
            #pragma unroll
            for (int j = 0; j < 8; ++j)
                x1T[(d + j - 64) * XTSTR + n] = bv[j];
        }
    }
    __syncthreads();     // the ONLY barrier

    const int wave = tid >> 6, lane = tid & 63, quad = lane >> 4, l15 = lane & 15;
    const int wq = wave;                 // wave owns out0 cols [wq*16, wq*16+16)
    const f32x4 z4 = {0.f, 0.f, 0.f, 0.f};
    const int ph64 = (blockIdx.x * 5) & 63;   // per-block K-loop phase (decorrelate L2 lines)
    const int ph32 = (blockIdx.x * 5) & 31;

    f32x4 o0[4];                         // out0 accumulators (live through S and H only)
    #pragma unroll
    for (int mt = 0; mt < 4; ++mt) o0[mt] = z4;

    // ================ stage S: g = x0 @ Ŵ0 (K=64, N=4096), contract with x0 ================
    {
        short8 aS[4][2];
        #pragma unroll
        for (int mt = 0; mt < 4; ++mt)
            #pragma unroll
            for (int ks = 0; ks < 2; ++ks) {
                U4S8 t; t.u = *(const uint4*)&A_S[(mt * 16 + l15) * ASTR + ks * 32 + quad * 8];
                aS[mt][ks] = t.s;
            }
        const u16* bp = ws + BG_OFF + (u32)wq * 1024 + lane * 8;   // + u*4096 per u
        U4S8 b0[2], b1[2];
        b0[0].u = *(const uint4*)(bp + ph64 * 4096);
        b1[0].u = *(const uint4*)(bp + ph64 * 4096 + 512);
        {
            int p1 = ((ph64 + 1) & 63) * 4096;
            b0[1].u = *(const uint4*)(bp + p1);
            b1[1].u = *(const uint4*)(bp + p1 + 512);
        }
        #pragma unroll 2
        for (int t = 0; t < 64; ++t) {
            const int c = t & 1;
            const int u = (ph64 + t) & 63;
            short8 B0 = b0[c].s, B1 = b1[c].s;
            {   // UNCONDITIONAL distance-2 prefetch (wraps; keeps vmcnt counts precise)
                int pp = ((ph64 + t + 2) & 63) * 4096;
                b0[c].u = *(const uint4*)(bp + pp);
                b1[c].u = *(const uint4*)(bp + pp + 512);
            }
            f32x4 acc[4];
            #pragma unroll
            for (int mt = 0; mt < 4; ++mt) acc[mt] = z4;
            #pragma unroll
            for (int mt = 0; mt < 4; ++mt)
                acc[mt] = __builtin_amdgcn_mfma_f32_16x16x32_bf16(aS[mt][0], B0, acc[mt], 0, 0, 0);
            #pragma unroll
            for (int mt = 0; mt < 4; ++mt)
                acc[mt] = __builtin_amdgcn_mfma_f32_16x16x32_bf16(aS[mt][1], B1, acc[mt], 0, 0, 0);
            #pragma unroll
            for (int mt = 0; mt < 4; ++mt) {
                f32x4 xq = bf4(*(const uint2*)&x0T[u * XTSTR + mt * 16 + quad * 4]);
                o0[mt] += xq * acc[mt];
            }
        }
    }

    // ================ stage H: h = x1 @ Ŵ1 (K=32, N=2048), merged i, contract -> out0 ================
    {
        short8 aH[12];                   // built from x1T (A_H eliminated; one-time gather)
        #pragma unroll
        for (int i = 0; i < 3; ++i)
            #pragma unroll
            for (int m = 0; m < 4; ++m) {
                const int n = m * 16 + l15;
                union { short8 s; u16 e[8]; } t;
                #pragma unroll
                for (int j = 0; j < 8; ++j)
                    t.e[j] = x1T[((quad * 8 + j) * 3 + i) * XTSTR + n];
                aH[i * 4 + m] = t.s;
            }
        const u16* bp = ws + BH_OFF + (u32)wq * 512 + lane * 8;    // + u*2048 per u
        U4S8 bb[2];
        bb[0].u = *(const uint4*)(bp + ph32 * 2048);
        bb[1].u = *(const uint4*)(bp + ((ph32 + 1) & 31) * 2048);
        #pragma unroll 2
        for (int t = 0; t < 32; ++t) {
            const int c = t & 1;
            const int u = (ph32 + t) & 31;
            short8 B = bb[c].s;
            bb[c].u = *(const uint4*)(bp + ((ph32 + t + 2) & 31) * 2048);   // unconditional
            #pragma unroll
            for (int i = 0; i < 3; ++i) {
                f32x4 acc[4];
                #pragma unroll
                for (int m = 0; m < 4; ++m) acc[m] = z4;
                #pragma unroll
                for (int m = 0; m < 4; ++m)
                    acc[m] = __builtin_amdgcn_mfma_f32_16x16x32_bf16(aH[i * 4 + m], B, acc[m], 0, 0, 0);
                #pragma unroll
                for (int m = 0; m < 4; ++m) {
                    f32x4 xq = bf4(*(const uint2*)&x1T[(u * 3 + i) * XTSTR + m * 16 + quad * 4]);
                    o0[m] += xq * acc[m];
                }
            }
        }
    }

    // ---- out0 epilogue (o0 dies here, before stage T) ----
    {
        const float C0v = 0.019581512f;              // sqrt(1/2608)
        #pragma unroll
        for (int mt = 0; mt < 4; ++mt)
            #pragma unroll
            for (int rr = 0; rr < 4; ++rr) {
                int node = node0 + mt * 16 + quad * 4 + rr;
                if (node < N_NODES)
                    out[node * 160 + wq * 16 + l15] = C0v * o0[mt][rr];
            }
    }

    // ================ stage T: t = x0 @ W3' (K=64, N=1024), contract with x1 -> out1 ================
    {
        const int mh = wave >> 1, wh = wave & 1;     // wave owns rows [mh*32..+32), w-cols [wh*16..+16)
        short8 aT[2][2];
        #pragma unroll
        for (int m = 0; m < 2; ++m)
            #pragma unroll
            for (int ks = 0; ks < 2; ++ks) {
                U4S8 t; t.u = *(const uint4*)&A_S[((mh * 2 + m) * 16 + l15) * ASTR + ks * 32 + quad * 8];
                aT[m][ks] = t.s;
            }
        f32x4 o1[3][2];
        #pragma unroll
        for (int i = 0; i < 3; ++i)
            #pragma unroll
            for (int m = 0; m < 2; ++m) o1[i][m] = z4;

        const u16* bp = ws + BT_OFF + (u32)wh * 1024 + lane * 8;   // + u*2048 per u
        U4S8 b0[2], b1[2];
        b0[0].u = *(const uint4*)(bp + ph32 * 2048);
        b1[0].u = *(const uint4*)(bp + ph32 * 2048 + 512);
        {
            int p1 = ((ph32 + 1) & 31) * 2048;
            b0[1].u = *(const uint4*)(bp + p1);
            b1[1].u = *(const uint4*)(bp + p1 + 512);
        }
        #pragma unroll 2
        for (int t = 0; t < 32; ++t) {
            const int c = t & 1;
            const int u = (ph32 + t) & 31;
            short8 B0 = b0[c].s, B1 = b1[c].s;
            {   // UNCONDITIONAL distance-2 prefetch (wraps)
                int pp = ((ph32 + t + 2) & 31) * 2048;
                b0[c].u = *(const uint4*)(bp + pp);
                b1[c].u = *(const uint4*)(bp + pp + 512);
            }
            f32x4 acc[2];
            #pragma unroll
            for (int m = 0; m < 2; ++m) acc[m] = z4;
            #pragma unroll
            for (int m = 0; m < 2; ++m)
                acc[m] = __builtin_amdgcn_mfma_f32_16x16x32_bf16(aT[m][0], B0, acc[m], 0, 0, 0);
            #pragma unroll
            for (int m = 0; m < 2; ++m)
                acc[m] = __builtin_amdgcn_mfma_f32_16x16x32_bf16(aT[m][1], B1, acc[m], 0, 0, 0);
            #pragma unroll
            for (int i = 0; i < 3; ++i)
                #pragma unroll
                for (int m = 0; m < 2; ++m) {
                    f32x4 xq = bf4(*(const uint2*)&x1T[(u * 3 + i) * XTSTR + (mh * 2 + m) * 16 + quad * 4]);
                    o1[i][m] += xq * acc[m];
                }
        }
        const float S1 = 0.022097087f;               // C1/sqrt(3) = sqrt(1/2048)
        #pragma unroll
        for (int i = 0; i < 3; ++i)
            #pragma unroll
            for (int m = 0; m < 2; ++m)
                #pragma unroll
                for (int rr = 0; rr < 4; ++rr) {
                    int node = node0 + (mh * 2 + m) * 16 + quad * 4 + rr;
                    if (node < N_NODES)
                        out[node * 160 + 64 + (wh * 16 + l15) * 3 + i] = S1 * o1[i][m][rr];
                }
    }
}

extern "C" void kernel_launch(void* const* d_in, const int* in_sizes, int n_in,
                              void* d_out, int out_size, void* d_ws, size_t ws_size,
                              hipStream_t stream) {
    const float* feats = (const float*)d_in[0];
    const float* msgs  = (const float*)d_in[1];
    const float* W1    = (const float*)d_in[2];
    const float* W2    = (const float*)d_in[3];
    const float* W3    = (const float*)d_in[4];
    const float* W4    = (const float*)d_in[5];
    const float* W5    = (const float*)d_in[6];
    float* out = (float*)d_out;
    u16* ws = (u16*)d_ws;     // needs 786432 B

    hipLaunchKernelGGL(pack_kernel, dim3(192), dim3(256), 0, stream,
                       W1, W2, W3, W4, W5, ws);
    hipLaunchKernelGGL(node_block_kernel, dim3((N_NODES + NB - 1) / NB), dim3(256), 0, stream,
                       feats, msgs, ws, out);
}

// Round 6
// 181.119 us; speedup vs baseline: 3.4415x; 1.0267x over previous
//
#include <hip/hip_runtime.h>

typedef unsigned short u16;
typedef unsigned int u32;

#define N_NODES 50000
#define NB      32

// ws regions (u16 element offsets). Total 393216 u16 = 786432 bytes.
#define BG_OFF  0         // g-part B: N=4096 cols (j=u*64+w), K=64
#define BT_OFF  262144    // t-part B: N=1024 cols (j=u*32+w), K=64
#define BH_OFF  327680    // h-part B: N=2048 cols (j=u*64+w), K=32

// LDS strides
#define ASTR   72   // A_S row stride (u16): 144B
#define XTSTR  36   // x0T/x1T row stride (u16 bf16): 72B (cols n < 32)

typedef __attribute__((ext_vector_type(8))) short short8;
typedef __attribute__((ext_vector_type(4))) float f32x4;
union U4S8 { uint4 u; short8 s; };

__device__ __forceinline__ u16 f2bf(float f) {   // RNE f32 -> bf16
    u32 u = __float_as_uint(f);
    return (u16)((u + 0x7fffu + ((u >> 16) & 1u)) >> 16);
}
__device__ __forceinline__ f32x4 bf4(uint2 q) {  // 4 packed bf16 -> f32x4
    f32x4 r;
    r[0] = __uint_as_float(q.x << 16);
    r[1] = __uint_as_float(q.x & 0xffff0000u);
    r[2] = __uint_as_float(q.y << 16);
    r[3] = __uint_as_float(q.y & 0xffff0000u);
    return r;
}

// ---------------- pack: output-indexed, coalesced uint4 writes, gather reads ----------------
// B-frag layout (16x16x32): slot-in-ntile = ks*512 + (((v>>3)&3)*16 + (j&15))*8 + (v&7)
// BG/BT: ntile = j>>4 with 64 k's (ks=v>>5); BH: K=32, no ks term.
__global__ __launch_bounds__(256)
void pack_kernel(const float* __restrict__ W1, const float* __restrict__ W2,
                 const float* __restrict__ W3, const float* __restrict__ W4,
                 const float* __restrict__ W5, u16* __restrict__ ws) {
    const float INV_SQRT3 = 0.57735026918962576f;
    int T = blockIdx.x * 256 + threadIdx.x;       // 49152 threads
    int slot0 = T * 8;                             // 8 consecutive slots (jj = v&7 = 0..7)
    float vals[8];
    if (slot0 < BT_OFF) {                          // ---- BG: Ŵ0[v, u, w] ----
        int ntile = slot0 >> 10, rem = slot0 & 1023;
        int ks = rem >> 9, q = (rem & 511) >> 3;
        int vbase = ks * 32 + (q >> 4) * 8;
        int j = ntile * 16 + (q & 15);
        int u = j >> 6, w = j & 63;
        #pragma unroll
        for (int jj = 0; jj < 8; ++jj) {
            int v = vbase + jj;
            if (v == u) vals[jj] = W2[u * 64 + w];
            else {
                int a = min(u, v), b = max(u, v);
                int p = a * (127 - a) / 2 + (b - a - 1);   // triu64 k=1 row-major
                vals[jj] = 0.5f * W1[p * 64 + w];
            }
        }
    } else if (slot0 < BH_OFF) {                   // ---- BT: W3[u, v, w], col j=u*32+w ----
        int s = slot0 - BT_OFF;
        int ntile = s >> 10, rem = s & 1023;
        int ks = rem >> 9, q = (rem & 511) >> 3;
        int vbase = ks * 32 + (q >> 4) * 8;
        int j = ntile * 16 + (q & 15);
        int u = j >> 5, w = j & 31;
        #pragma unroll
        for (int jj = 0; jj < 8; ++jj)
            vals[jj] = W3[(u * 64 + (vbase + jj)) * 32 + w];
    } else {                                       // ---- BH: Ŵ1[v, u, w], K=32 ----
        int s = slot0 - BH_OFF;
        int ntile = s >> 9, q = (s & 511) >> 3;
        int vbase = (q >> 4) * 8;
        int j = ntile * 16 + (q & 15);
        int u = j >> 6, w = j & 63;
        #pragma unroll
        for (int jj = 0; jj < 8; ++jj) {
            int v = vbase + jj;
            if (v == u) vals[jj] = W5[u * 64 + w] * INV_SQRT3;
            else {
                int a = min(u, v), b = max(u, v);
                int p = a * (63 - a) / 2 + (b - a - 1);    // triu32 k=1
                vals[jj] = (0.5f * INV_SQRT3) * W4[p * 64 + w];
            }
        }
    }
    uint4 o;
    o.x = ((u32)f2bf(vals[1]) << 16) | f2bf(vals[0]);
    o.y = ((u32)f2bf(vals[3]) << 16) | f2bf(vals[2]);
    o.z = ((u32)f2bf(vals[5]) << 16) | f2bf(vals[4]);
    o.w = ((u32)f2bf(vals[7]) << 16) | f2bf(vals[6]);
    *(uint4*)(ws + slot0) = o;                     // coalesced 16B store
}

// ---------------- main fused kernel: NB=32 (2x grid = 6 blocks/CU), same loop structure ----------------
__global__ __launch_bounds__(256, 3)
void node_block_kernel(const float* __restrict__ feats, const float* __restrict__ msgs,
                       const u16* __restrict__ ws, float* __restrict__ out) {
    __shared__ u16 A_S[32 * ASTR];       //  4608 B  bf16 x0 tile   (rows n<32, cols v<64)
    __shared__ u16 x0T[64 * XTSTR];      //  4608 B  bf16 x0^T      ([v][n])
    __shared__ u16 x1T[96 * XTSTR];      //  6912 B  bf16 x1^T      ([u*3+i][n])
    // total 16128 B -> residency limited by VGPR/grid, not LDS

    const int tid = threadIdx.x;
    const int node0 = blockIdx.x * NB;

    // ---- staging: x = feats + msgs, scattered into LDS forms (640 chunks of 8) ----
    for (int k = 0; k < 3; ++k) {
        int chunk = tid + k * 256;
        if (chunk < 640) {
            int idx = chunk * 8;                 // 160 % 8 == 0: never straddles nodes
            int n = (u32)idx / 160u;
            int d = idx - n * 160;
            int g = node0 * 160 + idx;
            float v[8];
            if (g + 8 <= N_NODES * 160) {
                float4 fa0 = *(const float4*)(feats + g);
                float4 fa1 = *(const float4*)(feats + g + 4);
                float4 fb0 = *(const float4*)(msgs + g);
                float4 fb1 = *(const float4*)(msgs + g + 4);
                v[0]=fa0.x+fb0.x; v[1]=fa0.y+fb0.y; v[2]=fa0.z+fb0.z; v[3]=fa0.w+fb0.w;
                v[4]=fa1.x+fb1.x; v[5]=fa1.y+fb1.y; v[6]=fa1.z+fb1.z; v[7]=fa1.w+fb1.w;
            } else {
                #pragma unroll
                for (int j = 0; j < 8; ++j) v[j] = 0.f;
            }
            u16 bv[8];
            #pragma unroll
            for (int j = 0; j < 8; ++j) bv[j] = f2bf(v[j]);
            if (d < 64) {                        // x0 chunk
                uint4 pk;
                pk.x = ((u32)bv[1] << 16) | bv[0];
                pk.y = ((u32)bv[3] << 16) | bv[2];
                pk.z = ((u32)bv[5] << 16) | bv[4];
                pk.w = ((u32)bv[7] << 16) | bv[6];
                *(uint4*)&A_S[n * ASTR + d] = pk;
                #pragma unroll
                for (int j = 0; j < 8; ++j) x0T[(d + j) * XTSTR + n] = bv[j];
            } else {                             // x1 chunk: x1T rows dd = u*3+i directly
                #pragma unroll
                for (int j = 0; j < 8; ++j)
                    x1T[(d + j - 64) * XTSTR + n] = bv[j];
            }
        }
    }
    __syncthreads();     // the ONLY barrier

    const int wave = tid >> 6, lane = tid & 63, quad = lane >> 4, l15 = lane & 15;
    const int wq = wave;                 // wave owns out0 cols [wq*16, wq*16+16)
    const f32x4 z4 = {0.f, 0.f, 0.f, 0.f};
    const int ph64 = (blockIdx.x * 5) & 63;   // per-block K-loop phase (decorrelate L2 lines)
    const int ph32 = (blockIdx.x * 5) & 31;

    f32x4 o0[2];                         // out0 accumulators (live through S and H only)
    #pragma unroll
    for (int mt = 0; mt < 2; ++mt) o0[mt] = z4;

    // ================ stage S: g = x0 @ Ŵ0 (K=64, N=4096), contract with x0 ================
    {
        short8 aS[2][2];
        #pragma unroll
        for (int mt = 0; mt < 2; ++mt)
            #pragma unroll
            for (int ks = 0; ks < 2; ++ks) {
                U4S8 t; t.u = *(const uint4*)&A_S[(mt * 16 + l15) * ASTR + ks * 32 + quad * 8];
                aS[mt][ks] = t.s;
            }
        const u16* bp = ws + BG_OFF + (u32)wq * 1024 + lane * 8;   // + u*4096 per u
        U4S8 b0[2], b1[2];
        b0[0].u = *(const uint4*)(bp + ph64 * 4096);
        b1[0].u = *(const uint4*)(bp + ph64 * 4096 + 512);
        {
            int p1 = ((ph64 + 1) & 63) * 4096;
            b0[1].u = *(const uint4*)(bp + p1);
            b1[1].u = *(const uint4*)(bp + p1 + 512);
        }
        #pragma unroll 2
        for (int t = 0; t < 64; ++t) {
            const int c = t & 1;
            const int u = (ph64 + t) & 63;
            short8 B0 = b0[c].s, B1 = b1[c].s;
            {   // UNCONDITIONAL distance-2 prefetch (wraps; keeps vmcnt counts precise)
                int pp = ((ph64 + t + 2) & 63) * 4096;
                b0[c].u = *(const uint4*)(bp + pp);
                b1[c].u = *(const uint4*)(bp + pp + 512);
            }
            f32x4 acc[2];
            #pragma unroll
            for (int mt = 0; mt < 2; ++mt) acc[mt] = z4;
            #pragma unroll
            for (int mt = 0; mt < 2; ++mt)
                acc[mt] = __builtin_amdgcn_mfma_f32_16x16x32_bf16(aS[mt][0], B0, acc[mt], 0, 0, 0);
            #pragma unroll
            for (int mt = 0; mt < 2; ++mt)
                acc[mt] = __builtin_amdgcn_mfma_f32_16x16x32_bf16(aS[mt][1], B1, acc[mt], 0, 0, 0);
            #pragma unroll
            for (int mt = 0; mt < 2; ++mt) {
                f32x4 xq = bf4(*(const uint2*)&x0T[u * XTSTR + mt * 16 + quad * 4]);
                o0[mt] += xq * acc[mt];
            }
        }
    }

    // ================ stage H: h = x1 @ Ŵ1 (K=32, N=2048), merged i, contract -> out0 ================
    {
        short8 aH[6];                    // built from x1T (one-time gather)
        #pragma unroll
        for (int i = 0; i < 3; ++i)
            #pragma unroll
            for (int m = 0; m < 2; ++m) {
                const int n = m * 16 + l15;
                union { short8 s; u16 e[8]; } t;
                #pragma unroll
                for (int j = 0; j < 8; ++j)
                    t.e[j] = x1T[((quad * 8 + j) * 3 + i) * XTSTR + n];
                aH[i * 2 + m] = t.s;
            }
        const u16* bp = ws + BH_OFF + (u32)wq * 512 + lane * 8;    // + u*2048 per u
        U4S8 bb[2];
        bb[0].u = *(const uint4*)(bp + ph32 * 2048);
        bb[1].u = *(const uint4*)(bp + ((ph32 + 1) & 31) * 2048);
        #pragma unroll 2
        for (int t = 0; t < 32; ++t) {
            const int c = t & 1;
            const int u = (ph32 + t) & 31;
            short8 B = bb[c].s;
            bb[c].u = *(const uint4*)(bp + ((ph32 + t + 2) & 31) * 2048);   // unconditional
            #pragma unroll
            for (int i = 0; i < 3; ++i) {
                f32x4 acc[2];
                #pragma unroll
                for (int m = 0; m < 2; ++m) acc[m] = z4;
                #pragma unroll
                for (int m = 0; m < 2; ++m)
                    acc[m] = __builtin_amdgcn_mfma_f32_16x16x32_bf16(aH[i * 2 + m], B, acc[m], 0, 0, 0);
                #pragma unroll
                for (int m = 0; m < 2; ++m) {
                    f32x4 xq = bf4(*(const uint2*)&x1T[(u * 3 + i) * XTSTR + m * 16 + quad * 4]);
                    o0[m] += xq * acc[m];
                }
            }
        }
    }

    // ---- out0 epilogue (o0 dies here, before stage T) ----
    {
        const float C0v = 0.019581512f;              // sqrt(1/2608)
        #pragma unroll
        for (int mt = 0; mt < 2; ++mt)
            #pragma unroll
            for (int rr = 0; rr < 4; ++rr) {
                int node = node0 + mt * 16 + quad * 4 + rr;
                if (node < N_NODES)
                    out[node * 160 + wq * 16 + l15] = C0v * o0[mt][rr];
            }
    }

    // ================ stage T: t = x0 @ W3' (K=64, N=1024), contract with x1 -> out1 ================
    {
        const int mh = wave >> 1, wh = wave & 1;     // wave owns rows [mh*16..+16), w-cols [wh*16..+16)
        short8 aT[2];
        #pragma unroll
        for (int ks = 0; ks < 2; ++ks) {
            U4S8 t; t.u = *(const uint4*)&A_S[(mh * 16 + l15) * ASTR + ks * 32 + quad * 8];
            aT[ks] = t.s;
        }
        f32x4 o1[3];
        #pragma unroll
        for (int i = 0; i < 3; ++i) o1[i] = z4;

        const u16* bp = ws + BT_OFF + (u32)wh * 1024 + lane * 8;   // + u*2048 per u
        U4S8 b0[2], b1[2];
        b0[0].u = *(const uint4*)(bp + ph32 * 2048);
        b1[0].u = *(const uint4*)(bp + ph32 * 2048 + 512);
        {
            int p1 = ((ph32 + 1) & 31) * 2048;
            b0[1].u = *(const uint4*)(bp + p1);
            b1[1].u = *(const uint4*)(bp + p1 + 512);
        }
        #pragma unroll 2
        for (int t = 0; t < 32; ++t) {
            const int c = t & 1;
            const int u = (ph32 + t) & 31;
            short8 B0 = b0[c].s, B1 = b1[c].s;
            {   // UNCONDITIONAL distance-2 prefetch (wraps)
                int pp = ((ph32 + t + 2) & 31) * 2048;
                b0[c].u = *(const uint4*)(bp + pp);
                b1[c].u = *(const uint4*)(bp + pp + 512);
            }
            f32x4 acc = __builtin_amdgcn_mfma_f32_16x16x32_bf16(aT[0], B0, z4, 0, 0, 0);
            acc = __builtin_amdgcn_mfma_f32_16x16x32_bf16(aT[1], B1, acc, 0, 0, 0);
            #pragma unroll
            for (int i = 0; i < 3; ++i) {
                f32x4 xq = bf4(*(const uint2*)&x1T[(u * 3 + i) * XTSTR + mh * 16 + quad * 4]);
                o1[i] += xq * acc;
            }
        }
        const float S1 = 0.022097087f;               // C1/sqrt(3) = sqrt(1/2048)
        #pragma unroll
        for (int i = 0; i < 3; ++i)
            #pragma unroll
            for (int rr = 0; rr < 4; ++rr) {
                int node = node0 + mh * 16 + quad * 4 + rr;
                if (node < N_NODES)
                    out[node * 160 + 64 + (wh * 16 + l15) * 3 + i] = S1 * o1[i][rr];
            }
    }
}

extern "C" void kernel_launch(void* const* d_in, const int* in_sizes, int n_in,
                              void* d_out, int out_size, void* d_ws, size_t ws_size,
                              hipStream_t stream) {
    const float* feats = (const float*)d_in[0];
    const float* msgs  = (const float*)d_in[1];
    const float* W1    = (const float*)d_in[2];
    const float* W2    = (const float*)d_in[3];
    const float* W3    = (const float*)d_in[4];
    const float* W4    = (const float*)d_in[5];
    const float* W5    = (const float*)d_in[6];
    float* out = (float*)d_out;
    u16* ws = (u16*)d_ws;     // needs 786432 B

    hipLaunchKernelGGL(pack_kernel, dim3(192), dim3(256), 0, stream,
                       W1, W2, W3, W4, W5, ws);
    hipLaunchKernelGGL(node_block_kernel, dim3((N_NODES + NB - 1) / NB), dim3(256), 0, stream,
                       feats, msgs, ws, out);
}